// Round 1
// baseline (199.855 us; speedup 1.0000x reference)
//
#include <hip/hip_runtime.h>
#include <stdint.h>

#define DM 256
#define NHEADS 8
#define DH 32
#define SEQ 2048
#define NB 4
#define MTOT (NB*SEQ)

typedef __attribute__((ext_vector_type(8))) __bf16 bf16x8;
typedef __attribute__((ext_vector_type(4))) short s16x4;
typedef __attribute__((ext_vector_type(4))) float f32x4;

__device__ inline short f2bf(float f){
  uint32_t u = __builtin_bit_cast(uint32_t, f);
  u += 0x7fffu + ((u >> 16) & 1u);
  return (short)(u >> 16);
}

// ---------------------------------------------------------------------------
// QKV projection: out = X @ W^T + b   (torch Linear), M=8192, N=256, K=256
// mode (blockIdx.z): 0 -> Qh [b,h,l,d]; 1 -> Kh [b,h,l,d]; 2 -> Vt [b,h,d,l]
// block = 256 thr = 4 waves; tile 64(M) x 64(N); wave w owns rows w*16..+15.
// ---------------------------------------------------------------------------
__global__ __launch_bounds__(256) void qkv_proj(
    const float* __restrict__ Xq, const float* __restrict__ Xk, const float* __restrict__ Xv,
    const float* __restrict__ Wq, const float* __restrict__ bq,
    const float* __restrict__ Wk, const float* __restrict__ bk,
    const float* __restrict__ Wv, const float* __restrict__ bv,
    short* __restrict__ Qh, short* __restrict__ Kh, short* __restrict__ Vt)
{
  const int mode = blockIdx.z;
  const float* X    = mode==0 ? Xq : (mode==1 ? Xk : Xv);
  const float* W    = mode==0 ? Wq : (mode==1 ? Wk : Wv);
  const float* bias = mode==0 ? bq : (mode==1 ? bk : bv);
  short* dst        = mode==0 ? Qh : (mode==1 ? Kh : Vt);

  const int wid = threadIdx.x >> 6, lane = threadIdx.x & 63;
  const int lr = lane & 15, lg = lane >> 4;
  const int m0 = blockIdx.x*64 + wid*16;
  const int nf0 = blockIdx.y*4;

  f32x4 acc[4] = {};

  #pragma unroll
  for (int kc = 0; kc < 8; ++kc) {
    const int k0 = kc*32 + lg*8;
    const float* ap = X + (size_t)(m0 + lr)*DM + k0;
    bf16x8 a;
    #pragma unroll
    for (int j=0;j<8;j++) a[j] = (__bf16)ap[j];
    #pragma unroll
    for (int nfi=0; nfi<4; ++nfi) {
      const float* bp = W + (size_t)((nf0+nfi)*16 + lr)*DM + k0;
      bf16x8 bfr;
      #pragma unroll
      for (int j=0;j<8;j++) bfr[j] = (__bf16)bp[j];
      acc[nfi] = __builtin_amdgcn_mfma_f32_16x16x32_bf16(a, bfr, acc[nfi], 0,0,0);
    }
  }

  // C/D layout: col = nf*16 + lr, row(local) = lg*4 + r   [measured m89]
  const int bb  = m0 >> 11;            // batch (64 | 2048, no straddle)
  const int li0 = (m0 & (SEQ-1)) + lg*4;
  #pragma unroll
  for (int nfi=0; nfi<4; ++nfi) {
    const int col = (nf0+nfi)*16 + lr;
    const float bv_ = bias[col];
    const int h = col >> 5, d = col & 31;
    if (mode < 2) {
      #pragma unroll
      for (int r=0;r<4;r++)
        dst[((size_t)(bb*NHEADS + h)*SEQ + (li0 + r))*DH + d] = f2bf(acc[nfi][r] + bv_);
    } else {
      s16x4 pk;
      #pragma unroll
      for (int r=0;r<4;r++) pk[r] = f2bf(acc[nfi][r] + bv_);
      *(s16x4*)(dst + ((size_t)(bb*NHEADS + h)*DH + d)*SEQ + li0) = pk;
    }
  }
}

// ---------------------------------------------------------------------------
// Flash attention. grid = (SEQ/64, B*H). 4 waves, wave owns 16 q-rows.
// KVBLK=64. Dh=32 = one MFMA K-step. P goes C-layout -> A-layout via
// XOR-swizzled per-wave LDS (2KB).
// ---------------------------------------------------------------------------
__global__ __launch_bounds__(256) void attn(
    const short* __restrict__ Qh, const short* __restrict__ Kh,
    const short* __restrict__ Vt, short* __restrict__ ctx)
{
  __shared__ __align__(16) short Plds[4][16*64];
  const int wid = threadIdx.x >> 6, lane = threadIdx.x & 63;
  const int lr = lane & 15, lg = lane >> 4;
  const int bh = blockIdx.y;
  const int q0 = blockIdx.x*64 + wid*16;
  const float scale = 0.17677669529663687f;  // 1/sqrt(32)

  // Q A-fragment: row = lr, k(=d) = lg*8 + j
  const bf16x8 qf = *(const bf16x8*)(Qh + ((size_t)bh*SEQ + q0 + lr)*DH + lg*8);

  f32x4 O0 = {}, O1 = {};
  float mrun[4], lrun[4];
  #pragma unroll
  for (int r=0;r<4;r++){ mrun[r] = -1e30f; lrun[r] = 0.f; }

  short* myP = &Plds[wid][0];
  const f32x4 zf = {};

  for (int t = 0; t < SEQ/64; ++t) {
    const int kvb = t*64;
    f32x4 S[4];
    #pragma unroll
    for (int n=0;n<4;n++){
      // B-frag of K^T: col = kv = n*16+lr, k(=d) = lg*8+j -> contiguous row of Kh
      bf16x8 kf = *(const bf16x8*)(Kh + ((size_t)bh*SEQ + kvb + n*16 + lr)*DH + lg*8);
      S[n] = __builtin_amdgcn_mfma_f32_16x16x32_bf16(qf, kf, zf, 0,0,0);
    }
    // rows (lg*4+r) spread over 16-lane group lg; reduce across lr lanes
    float tmax[4];
    #pragma unroll
    for (int r=0;r<4;r++) tmax[r] = -1e30f;
    #pragma unroll
    for (int n=0;n<4;n++)
      #pragma unroll
      for (int r=0;r<4;r++){ S[n][r] *= scale; tmax[r] = fmaxf(tmax[r], S[n][r]); }
    #pragma unroll
    for (int off=1; off<16; off<<=1)
      #pragma unroll
      for (int r=0;r<4;r++) tmax[r] = fmaxf(tmax[r], __shfl_xor(tmax[r], off));

    float corr[4], rsum[4];
    #pragma unroll
    for (int r=0;r<4;r++){
      float mn = fmaxf(mrun[r], tmax[r]);
      corr[r] = __expf(mrun[r] - mn);
      mrun[r] = mn;
      rsum[r] = 0.f;
    }
    #pragma unroll
    for (int n=0;n<4;n++)
      #pragma unroll
      for (int r=0;r<4;r++){ float p = __expf(S[n][r] - mrun[r]); S[n][r] = p; rsum[r] += p; }
    #pragma unroll
    for (int off=1; off<16; off<<=1)
      #pragma unroll
      for (int r=0;r<4;r++) rsum[r] += __shfl_xor(rsum[r], off);
    #pragma unroll
    for (int r=0;r<4;r++){
      lrun[r] = lrun[r]*corr[r] + rsum[r];
      O0[r] *= corr[r]; O1[r] *= corr[r];
    }

    // P (C-layout) -> LDS, XOR-swizzled to kill the 128B-stride conflict
    #pragma unroll
    for (int n=0;n<4;n++){
      #pragma unroll
      for (int r=0;r<4;r++){
        const int row = lg*4 + r;
        const int byt = (row*128 + (lr + 16*n)*2) ^ ((row&7)<<4);
        *(short*)((char*)myP + byt) = f2bf(S[n][r]);
      }
    }
    __syncthreads();

    // PV: A = P[16,64] (two K=32 chunks), B = V[64,32] from transposed Vt
    #pragma unroll
    for (int kc=0;kc<2;kc++){
      const int rbyte = (lr*128 + (kc*32 + lg*8)*2) ^ ((lr&7)<<4);
      bf16x8 pf = *(const bf16x8*)((const char*)myP + rbyte);
      bf16x8 v0 = *(const bf16x8*)(Vt + ((size_t)bh*DH + lr)*SEQ + kvb + kc*32 + lg*8);
      O0 = __builtin_amdgcn_mfma_f32_16x16x32_bf16(pf, v0, O0, 0,0,0);
      bf16x8 v1 = *(const bf16x8*)(Vt + ((size_t)bh*DH + 16 + lr)*SEQ + kvb + kc*32 + lg*8);
      O1 = __builtin_amdgcn_mfma_f32_16x16x32_bf16(pf, v1, O1, 0,0,0);
    }
    __syncthreads();
  }

  // finalize: ctx[b, l, h*32 + d] bf16
  const int bb = bh >> 3, h = bh & 7;
  #pragma unroll
  for (int r=0;r<4;r++){
    const float inv = 1.0f / lrun[r];
    const int m = q0 + lg*4 + r;
    short* cp = ctx + ((size_t)(bb*SEQ + m))*DM + h*DH;
    cp[lr]      = f2bf(O0[r]*inv);
    cp[16 + lr] = f2bf(O1[r]*inv);
  }
}

// ---------------------------------------------------------------------------
// out = ctx @ Wo^T + bo; x = out + query; LayerNorm(x) -> fp32 out
// wave owns 16 rows x all 256 cols (16 n-frags) so LN reduces in-wave.
// ---------------------------------------------------------------------------
__global__ __launch_bounds__(256) void out_ln(
    const short* __restrict__ ctx, const float* __restrict__ Wo,
    const float* __restrict__ bo, const float* __restrict__ resid,
    const float* __restrict__ ln_g, const float* __restrict__ ln_b,
    float* __restrict__ out)
{
  const int wid = threadIdx.x >> 6, lane = threadIdx.x & 63;
  const int lr = lane & 15, lg = lane >> 4;
  const int m0 = blockIdx.x*64 + wid*16;

  f32x4 acc[16] = {};
  #pragma unroll
  for (int kc=0; kc<8; ++kc) {
    const int k0 = kc*32 + lg*8;
    bf16x8 a = *(const bf16x8*)(ctx + (size_t)(m0 + lr)*DM + k0);
    #pragma unroll
    for (int nf=0; nf<16; ++nf) {
      const float* bp = Wo + (size_t)(nf*16 + lr)*DM + k0;
      bf16x8 bfr;
      #pragma unroll
      for (int j=0;j<8;j++) bfr[j] = (__bf16)bp[j];
      acc[nf] = __builtin_amdgcn_mfma_f32_16x16x32_bf16(a, bfr, acc[nf], 0,0,0);
    }
  }

  #pragma unroll
  for (int r=0;r<4;r++) {
    const int m = m0 + lg*4 + r;
    float xv[16]; float s = 0.f, s2 = 0.f;
    #pragma unroll
    for (int nf=0; nf<16; ++nf) {
      const int col = nf*16 + lr;
      float v = acc[nf][r] + bo[col] + resid[(size_t)m*DM + col];
      xv[nf] = v; s += v; s2 += v*v;
    }
    #pragma unroll
    for (int off=1; off<16; off<<=1) { s += __shfl_xor(s, off); s2 += __shfl_xor(s2, off); }
    const float mean = s * (1.0f/DM);
    const float var  = s2 * (1.0f/DM) - mean*mean;
    const float rstd = rsqrtf(var + 1e-5f);
    #pragma unroll
    for (int nf=0; nf<16; ++nf) {
      const int col = nf*16 + lr;
      out[(size_t)m*DM + col] = (xv[nf] - mean)*rstd*ln_g[col] + ln_b[col];
    }
  }
}

extern "C" void kernel_launch(void* const* d_in, const int* in_sizes, int n_in,
                              void* d_out, int out_size, void* d_ws, size_t ws_size,
                              hipStream_t stream) {
  const float* query = (const float*)d_in[0];
  const float* key   = (const float*)d_in[1];
  const float* value = (const float*)d_in[2];
  const float* Wq    = (const float*)d_in[3];
  const float* bq    = (const float*)d_in[4];
  const float* Wk    = (const float*)d_in[5];
  const float* bk    = (const float*)d_in[6];
  const float* Wv    = (const float*)d_in[7];
  const float* bv    = (const float*)d_in[8];
  const float* Wo    = (const float*)d_in[9];
  const float* bo    = (const float*)d_in[10];
  const float* ln_g  = (const float*)d_in[11];
  const float* ln_b  = (const float*)d_in[12];
  float* out = (float*)d_out;

  const size_t HSZ = (size_t)NB*NHEADS*SEQ*DH;  // 2,097,152 elems
  short* Qh  = (short*)d_ws;
  short* Kh  = Qh + HSZ;
  short* Vt  = Kh + HSZ;
  short* ctx = Vt + HSZ;   // [B, L, 256] bf16; total ws use = 16 MB

  qkv_proj<<<dim3(MTOT/64, 4, 3), 256, 0, stream>>>(
      query, key, value, Wq, bq, Wk, bk, Wv, bv, Qh, Kh, Vt);
  attn<<<dim3(SEQ/64, NB*NHEADS), 256, 0, stream>>>(Qh, Kh, Vt, ctx);
  out_ln<<<dim3(MTOT/64), 256, 0, stream>>>(ctx, Wo, bo, query, ln_g, ln_b, out);
}

// Round 2
// 146.337 us; speedup vs baseline: 1.3657x; 1.3657x over previous
//
#include <hip/hip_runtime.h>
#include <stdint.h>

#define DM 256
#define NHEADS 8
#define DH 32
#define SEQ 2048
#define NB 4
#define MTOT (NB*SEQ)

// scale * log2(e) : scores computed in exp2 domain
#define QSCALE 0.2550351270433207f

typedef __attribute__((ext_vector_type(8))) __bf16 bf16x8;
typedef __attribute__((ext_vector_type(4))) short s16x4;
typedef __attribute__((ext_vector_type(8))) short s16x8;
typedef __attribute__((ext_vector_type(4))) unsigned int u32x4;
typedef __attribute__((ext_vector_type(4))) float f32x4;

__device__ inline short f2bf(float f){
  uint32_t u = __builtin_bit_cast(uint32_t, f);
  u += 0x7fffu + ((u >> 16) & 1u);
  return (short)(u >> 16);
}

// ---------------------------------------------------------------------------
// prep: fp32 weights -> bf16 (Wq scaled by QSCALE). 4 x 65536 elems, 8/thread.
// ---------------------------------------------------------------------------
__global__ __launch_bounds__(256) void prep(
    const float* __restrict__ Wq, const float* __restrict__ Wk,
    const float* __restrict__ Wv, const float* __restrict__ Wo,
    short* __restrict__ Wqb, short* __restrict__ Wkb,
    short* __restrict__ Wvb, short* __restrict__ Wob)
{
  const int i = (blockIdx.x*256 + threadIdx.x)*8;
  const int seg = i >> 16;
  const int off = i & 65535;
  const float* src = seg==0?Wq: seg==1?Wk: seg==2?Wv:Wo;
  short* dst       = seg==0?Wqb: seg==1?Wkb: seg==2?Wvb:Wob;
  const float sc = (seg==0) ? QSCALE : 1.0f;
  float4 a = *(const float4*)(src + off);
  float4 b = *(const float4*)(src + off + 4);
  s16x8 o;
  o[0]=f2bf(a.x*sc); o[1]=f2bf(a.y*sc); o[2]=f2bf(a.z*sc); o[3]=f2bf(a.w*sc);
  o[4]=f2bf(b.x*sc); o[5]=f2bf(b.y*sc); o[6]=f2bf(b.z*sc); o[7]=f2bf(b.w*sc);
  *(s16x8*)(dst + off) = o;
}

// ---------------------------------------------------------------------------
// QKV projection with pre-converted bf16 W. out = X @ W^T + b.
// mode: 0 -> Qh [b,h,l,d] (pre-scaled); 1 -> Kh [b,h,l,d]; 2 -> Vt [b,h,d,l]
// ---------------------------------------------------------------------------
__global__ __launch_bounds__(256) void qkv_proj(
    const float* __restrict__ Xq, const float* __restrict__ Xk, const float* __restrict__ Xv,
    const short* __restrict__ Wqb, const short* __restrict__ Wkb, const short* __restrict__ Wvb,
    const float* __restrict__ bq, const float* __restrict__ bk, const float* __restrict__ bv,
    short* __restrict__ Qh, short* __restrict__ Kh, short* __restrict__ Vt)
{
  const int mode = blockIdx.z;
  const float* X    = mode==0 ? Xq : (mode==1 ? Xk : Xv);
  const short* Wb   = mode==0 ? Wqb : (mode==1 ? Wkb : Wvb);
  const float* bias = mode==0 ? bq : (mode==1 ? bk : bv);
  short* dst        = mode==0 ? Qh : (mode==1 ? Kh : Vt);
  const float bscale = (mode==0) ? QSCALE : 1.0f;

  const int wid = threadIdx.x >> 6, lane = threadIdx.x & 63;
  const int lr = lane & 15, lg = lane >> 4;
  const int m0 = blockIdx.x*64 + wid*16;
  const int nf0 = blockIdx.y*4;

  f32x4 acc[4] = {};

  #pragma unroll
  for (int kc = 0; kc < 8; ++kc) {
    const int k0 = kc*32 + lg*8;
    const float* ap = X + (size_t)(m0 + lr)*DM + k0;
    float4 a0 = *(const float4*)ap;
    float4 a1 = *(const float4*)(ap + 4);
    bf16x8 a;
    a[0]=(__bf16)a0.x; a[1]=(__bf16)a0.y; a[2]=(__bf16)a0.z; a[3]=(__bf16)a0.w;
    a[4]=(__bf16)a1.x; a[5]=(__bf16)a1.y; a[6]=(__bf16)a1.z; a[7]=(__bf16)a1.w;
    #pragma unroll
    for (int nfi=0; nfi<4; ++nfi) {
      bf16x8 b = *(const bf16x8*)(Wb + (size_t)((nf0+nfi)*16 + lr)*DM + k0);
      acc[nfi] = __builtin_amdgcn_mfma_f32_16x16x32_bf16(a, b, acc[nfi], 0,0,0);
    }
  }

  const int bb  = m0 >> 11;
  const int li0 = (m0 & (SEQ-1)) + lg*4;
  #pragma unroll
  for (int nfi=0; nfi<4; ++nfi) {
    const int col = (nf0+nfi)*16 + lr;
    const float bv_ = bias[col]*bscale;
    const int h = col >> 5, d = col & 31;
    if (mode < 2) {
      #pragma unroll
      for (int r=0;r<4;r++)
        dst[((size_t)(bb*NHEADS + h)*SEQ + (li0 + r))*DH + d] = f2bf(acc[nfi][r] + bv_);
    } else {
      s16x4 pk;
      #pragma unroll
      for (int r=0;r<4;r++) pk[r] = f2bf(acc[nfi][r] + bv_);
      *(s16x4*)(dst + ((size_t)(bb*NHEADS + h)*DH + d)*SEQ + li0) = pk;
    }
  }
}

// ---------------------------------------------------------------------------
// Flash attention, swapped-QK (S^T = mfma(K,Q)): softmax reduction is
// lane-local + 2 shfl_xor. P^T redistributed in-register (cvt_pk + bpermute),
// PV via O^T = mfma(V^T, P^T). No LDS, no barriers. Defer-max THR=8.
// Scores arrive pre-scaled by scale*log2e (folded into Wq) -> exp2 softmax.
// ---------------------------------------------------------------------------
__global__ __launch_bounds__(256) void attn(
    const short* __restrict__ Qh, const short* __restrict__ Kh,
    const short* __restrict__ Vt, short* __restrict__ ctx)
{
  const int wid = threadIdx.x >> 6, lane = threadIdx.x & 63;
  const int lr = lane & 15, lg = lane >> 4;
  const int bh = blockIdx.y;
  const int q0 = blockIdx.x*64 + wid*16;

  // Q B-frag: (q = q0+lr, k = d = lg*8+j)
  const bf16x8 qf = *(const bf16x8*)(Qh + ((size_t)bh*SEQ + q0 + lr)*DH + lg*8);
  const short* Kb = Kh + (size_t)bh*SEQ*DH;
  const short* Vb = Vt + (size_t)bh*DH*SEQ;

  f32x4 O0 = {}, O1 = {};
  float mrun = -1e30f, lrun = 0.f;
  const f32x4 zf = {};
  const int laneA = lr + ((lg & 1) << 5);  // src lane group a = (lg&1)*2
  const int csel  = lg >> 1;               // selects n within pulled pair

  for (int t = 0; t < SEQ/64; ++t) {
    const int kvb = t*64;
    f32x4 S[4];
    #pragma unroll
    for (int n=0;n<4;n++){
      // K A-frag: (kv = kvb + n*16 + lr, k = d = lg*8+j)
      bf16x8 kf = *(const bf16x8*)(Kb + (size_t)(kvb + n*16 + lr)*DH + lg*8);
      S[n] = __builtin_amdgcn_mfma_f32_16x16x32_bf16(kf, qf, zf, 0,0,0);
    }
    // lane holds S^T[kv = 16n + lg*4 + r][q = lr] : reduce in-lane then 2 shfl
    float gm = S[0][0];
    #pragma unroll
    for (int n=0;n<4;n++)
      #pragma unroll
      for (int r=0;r<4;r++) gm = fmaxf(gm, S[n][r]);
    gm = fmaxf(gm, __shfl_xor(gm, 16));
    gm = fmaxf(gm, __shfl_xor(gm, 32));

    if (!__all(gm - mrun <= 8.f)) {
      float mnew = fmaxf(mrun, gm);
      float corr = __builtin_amdgcn_exp2f(mrun - mnew);
      mrun = mnew; lrun *= corr;
      #pragma unroll
      for (int r=0;r<4;r++){ O0[r] *= corr; O1[r] *= corr; }
    }

    float p[16]; float rs = 0.f;
    #pragma unroll
    for (int n=0;n<4;n++)
      #pragma unroll
      for (int r=0;r<4;r++){
        float v = __builtin_amdgcn_exp2f(S[n][r] - mrun);
        p[n*4+r] = v; rs += v;
      }
    rs += __shfl_xor(rs, 16);
    rs += __shfl_xor(rs, 32);
    lrun += rs;

    // pack: P0[n] = bf16(p[n][0]) | bf16(p[n][1])<<16 ; P1[n] = r2,r3
    uint32_t P0[4], P1[4];
    #pragma unroll
    for (int n=0;n<4;n++){
      asm("v_cvt_pk_bf16_f32 %0, %1, %2" : "=v"(P0[n]) : "v"(p[n*4+0]), "v"(p[n*4+1]));
      asm("v_cvt_pk_bf16_f32 %0, %1, %2" : "=v"(P1[n]) : "v"(p[n*4+2]), "v"(p[n*4+3]));
    }

    // PV: per 32-kv chunk, build P^T B-frag (q=lr, kv=lg*8+j) from lanes
    // laneA/laneA+16, selecting n = kc*2 + (lg>>1).
    #pragma unroll
    for (int kc=0;kc<2;kc++){
      int x0 = __shfl((int)P0[kc*2],   laneA);
      int x1 = __shfl((int)P0[kc*2+1], laneA);
      int y0 = __shfl((int)P1[kc*2],   laneA);
      int y1 = __shfl((int)P1[kc*2+1], laneA);
      int z0 = __shfl((int)P0[kc*2],   laneA+16);
      int z1 = __shfl((int)P0[kc*2+1], laneA+16);
      int u0 = __shfl((int)P1[kc*2],   laneA+16);
      int u1 = __shfl((int)P1[kc*2+1], laneA+16);
      u32x4 pw;
      pw[0] = (uint32_t)(csel ? x1 : x0);
      pw[1] = (uint32_t)(csel ? y1 : y0);
      pw[2] = (uint32_t)(csel ? z1 : z0);
      pw[3] = (uint32_t)(csel ? u1 : u0);
      bf16x8 pf = __builtin_bit_cast(bf16x8, pw);
      // V^T A-frag: (d = half*16 + lr, kv = kvb + kc*32 + lg*8+j)
      bf16x8 v0 = *(const bf16x8*)(Vb + (size_t)lr*SEQ      + kvb + kc*32 + lg*8);
      bf16x8 v1 = *(const bf16x8*)(Vb + (size_t)(16+lr)*SEQ + kvb + kc*32 + lg*8);
      O0 = __builtin_amdgcn_mfma_f32_16x16x32_bf16(v0, pf, O0, 0,0,0);
      O1 = __builtin_amdgcn_mfma_f32_16x16x32_bf16(v1, pf, O1, 0,0,0);
    }
  }

  // O^T lane layout: q = lr, d = half*16 + lg*4 + r -> two 8B stores
  const int bb = bh >> 3, hh = bh & 7;
  const float inv = 1.0f / lrun;
  short* cp = ctx + ((size_t)(bb*SEQ) + q0 + lr)*DM + hh*DH + lg*4;
  s16x4 o0, o1;
  #pragma unroll
  for (int r=0;r<4;r++){ o0[r] = f2bf(O0[r]*inv); o1[r] = f2bf(O1[r]*inv); }
  *(s16x4*)cp = o0;
  *(s16x4*)(cp + 16) = o1;
}

// ---------------------------------------------------------------------------
// out = ctx @ Wo^T + bo; x = out + query; LayerNorm(x). 1 wave/block,
// 512 blocks so all CUs are busy. Wo pre-converted bf16.
// ---------------------------------------------------------------------------
__global__ __launch_bounds__(64) void out_ln(
    const short* __restrict__ ctx, const short* __restrict__ Wob,
    const float* __restrict__ bo, const float* __restrict__ resid,
    const float* __restrict__ ln_g, const float* __restrict__ ln_b,
    float* __restrict__ out)
{
  const int lane = threadIdx.x;
  const int lr = lane & 15, lg = lane >> 4;
  const int m0 = blockIdx.x*16;

  f32x4 acc[16] = {};
  #pragma unroll
  for (int kc=0; kc<8; ++kc) {
    const int k0 = kc*32 + lg*8;
    bf16x8 a = *(const bf16x8*)(ctx + (size_t)(m0 + lr)*DM + k0);
    #pragma unroll
    for (int nf=0; nf<16; ++nf) {
      bf16x8 b = *(const bf16x8*)(Wob + (size_t)(nf*16 + lr)*DM + k0);
      acc[nf] = __builtin_amdgcn_mfma_f32_16x16x32_bf16(a, b, acc[nf], 0,0,0);
    }
  }

  #pragma unroll
  for (int r=0;r<4;r++) {
    const int m = m0 + lg*4 + r;
    float xv[16]; float s = 0.f, s2 = 0.f;
    #pragma unroll
    for (int nf=0; nf<16; ++nf) {
      const int col = nf*16 + lr;
      float v = acc[nf][r] + bo[col] + resid[(size_t)m*DM + col];
      xv[nf] = v; s += v; s2 += v*v;
    }
    #pragma unroll
    for (int off=1; off<16; off<<=1) { s += __shfl_xor(s, off); s2 += __shfl_xor(s2, off); }
    const float mean = s * (1.0f/DM);
    const float var  = s2 * (1.0f/DM) - mean*mean;
    const float rstd = rsqrtf(var + 1e-5f);
    #pragma unroll
    for (int nf=0; nf<16; ++nf) {
      const int col = nf*16 + lr;
      out[(size_t)m*DM + col] = (xv[nf] - mean)*rstd*ln_g[col] + ln_b[col];
    }
  }
}

extern "C" void kernel_launch(void* const* d_in, const int* in_sizes, int n_in,
                              void* d_out, int out_size, void* d_ws, size_t ws_size,
                              hipStream_t stream) {
  const float* query = (const float*)d_in[0];
  const float* key   = (const float*)d_in[1];
  const float* value = (const float*)d_in[2];
  const float* Wq    = (const float*)d_in[3];
  const float* bq    = (const float*)d_in[4];
  const float* Wk    = (const float*)d_in[5];
  const float* bk    = (const float*)d_in[6];
  const float* Wv    = (const float*)d_in[7];
  const float* bv    = (const float*)d_in[8];
  const float* Wo    = (const float*)d_in[9];
  const float* bo    = (const float*)d_in[10];
  const float* ln_g  = (const float*)d_in[11];
  const float* ln_b  = (const float*)d_in[12];
  float* out = (float*)d_out;

  const size_t HSZ = (size_t)NB*NHEADS*SEQ*DH;   // 2,097,152
  short* Qh  = (short*)d_ws;
  short* Kh  = Qh + HSZ;
  short* Vt  = Kh + HSZ;
  short* ctx = Vt + HSZ;
  short* Wqb = ctx + (size_t)MTOT*DM;
  short* Wkb = Wqb + DM*DM;
  short* Wvb = Wkb + DM*DM;
  short* Wob = Wvb + DM*DM;   // total ws: ~17 MB

  prep<<<dim3(128), 256, 0, stream>>>(Wq, Wk, Wv, Wo, Wqb, Wkb, Wvb, Wob);
  qkv_proj<<<dim3(MTOT/64, 4, 3), 256, 0, stream>>>(
      query, key, value, Wqb, Wkb, Wvb, bq, bk, bv, Qh, Kh, Vt);
  attn<<<dim3(SEQ/64, NB*NHEADS), 256, 0, stream>>>(Qh, Kh, Vt, ctx);
  out_ln<<<dim3(MTOT/16), 64, 0, stream>>>(ctx, Wob, bo, query, ln_g, ln_b, out);
}

// Round 3
// 107.730 us; speedup vs baseline: 1.8551x; 1.3584x over previous
//
#include <hip/hip_runtime.h>
#include <stdint.h>

#define DM 256
#define NHEADS 8
#define DH 32
#define SEQ 2048
#define NB 4
#define MTOT (NB*SEQ)

// scale * log2(e) : scores computed in exp2 domain
#define QSCALE 0.2550351270433207f

typedef __attribute__((ext_vector_type(8))) __bf16 bf16x8;
typedef __attribute__((ext_vector_type(4))) short s16x4;
typedef __attribute__((ext_vector_type(8))) short s16x8;
typedef __attribute__((ext_vector_type(4))) unsigned int u32x4;
typedef __attribute__((ext_vector_type(4))) float f32x4;
typedef __attribute__((ext_vector_type(16))) float f32x16;

__device__ inline short f2bf(float f){
  uint32_t u = __builtin_bit_cast(uint32_t, f);
  u += 0x7fffu + ((u >> 16) & 1u);
  return (short)(u >> 16);
}

// ---------------------------------------------------------------------------
// prep: fp32 weights -> bf16 (Wq scaled by QSCALE). 4 x 65536 elems, 8/thread.
// ---------------------------------------------------------------------------
__global__ __launch_bounds__(256) void prep(
    const float* __restrict__ Wq, const float* __restrict__ Wk,
    const float* __restrict__ Wv, const float* __restrict__ Wo,
    short* __restrict__ Wqb, short* __restrict__ Wkb,
    short* __restrict__ Wvb, short* __restrict__ Wob)
{
  const int i = (blockIdx.x*256 + threadIdx.x)*8;
  const int seg = i >> 16;
  const int off = i & 65535;
  const float* src = seg==0?Wq: seg==1?Wk: seg==2?Wv:Wo;
  short* dst       = seg==0?Wqb: seg==1?Wkb: seg==2?Wvb:Wob;
  const float sc = (seg==0) ? QSCALE : 1.0f;
  float4 a = *(const float4*)(src + off);
  float4 b = *(const float4*)(src + off + 4);
  s16x8 o;
  o[0]=f2bf(a.x*sc); o[1]=f2bf(a.y*sc); o[2]=f2bf(a.z*sc); o[3]=f2bf(a.w*sc);
  o[4]=f2bf(b.x*sc); o[5]=f2bf(b.y*sc); o[6]=f2bf(b.z*sc); o[7]=f2bf(b.w*sc);
  *(s16x8*)(dst + off) = o;
}

// ---------------------------------------------------------------------------
// QKV projection with pre-converted bf16 W. out = X @ W^T + b.
// mode: 0 -> Qh [b,h,l,d] (pre-scaled); 1 -> Kh [b,h,l,d]; 2 -> Vt [b,h,d,l]
// ---------------------------------------------------------------------------
__global__ __launch_bounds__(256) void qkv_proj(
    const float* __restrict__ Xq, const float* __restrict__ Xk, const float* __restrict__ Xv,
    const short* __restrict__ Wqb, const short* __restrict__ Wkb, const short* __restrict__ Wvb,
    const float* __restrict__ bq, const float* __restrict__ bk, const float* __restrict__ bv,
    short* __restrict__ Qh, short* __restrict__ Kh, short* __restrict__ Vt)
{
  const int mode = blockIdx.z;
  const float* X    = mode==0 ? Xq : (mode==1 ? Xk : Xv);
  const short* Wb   = mode==0 ? Wqb : (mode==1 ? Wkb : Wvb);
  const float* bias = mode==0 ? bq : (mode==1 ? bk : bv);
  short* dst        = mode==0 ? Qh : (mode==1 ? Kh : Vt);
  const float bscale = (mode==0) ? QSCALE : 1.0f;

  const int wid = threadIdx.x >> 6, lane = threadIdx.x & 63;
  const int lr = lane & 15, lg = lane >> 4;
  const int m0 = blockIdx.x*64 + wid*16;
  const int nf0 = blockIdx.y*4;

  f32x4 acc[4] = {};

  #pragma unroll
  for (int kc = 0; kc < 8; ++kc) {
    const int k0 = kc*32 + lg*8;
    const float* ap = X + (size_t)(m0 + lr)*DM + k0;
    float4 a0 = *(const float4*)ap;
    float4 a1 = *(const float4*)(ap + 4);
    bf16x8 a;
    a[0]=(__bf16)a0.x; a[1]=(__bf16)a0.y; a[2]=(__bf16)a0.z; a[3]=(__bf16)a0.w;
    a[4]=(__bf16)a1.x; a[5]=(__bf16)a1.y; a[6]=(__bf16)a1.z; a[7]=(__bf16)a1.w;
    #pragma unroll
    for (int nfi=0; nfi<4; ++nfi) {
      bf16x8 b = *(const bf16x8*)(Wb + (size_t)((nf0+nfi)*16 + lr)*DM + k0);
      acc[nfi] = __builtin_amdgcn_mfma_f32_16x16x32_bf16(a, b, acc[nfi], 0,0,0);
    }
  }

  const int bb  = m0 >> 11;
  const int li0 = (m0 & (SEQ-1)) + lg*4;
  #pragma unroll
  for (int nfi=0; nfi<4; ++nfi) {
    const int col = (nf0+nfi)*16 + lr;
    const float bv_ = bias[col]*bscale;
    const int h = col >> 5, d = col & 31;
    if (mode < 2) {
      #pragma unroll
      for (int r=0;r<4;r++)
        dst[((size_t)(bb*NHEADS + h)*SEQ + (li0 + r))*DH + d] = f2bf(acc[nfi][r] + bv_);
    } else {
      s16x4 pk;
      #pragma unroll
      for (int r=0;r<4;r++) pk[r] = f2bf(acc[nfi][r] + bv_);
      *(s16x4*)(dst + ((size_t)(bb*NHEADS + h)*DH + d)*SEQ + li0) = pk;
    }
  }
}

// ---------------------------------------------------------------------------
// Flash attention, 32x32x16 MFMA, swapped-QK: S^T = mfma(K,Q) puts a full
// 16-elem kv-slice per lane -> softmax = 15 in-lane fmax + 1 shfl_xor(32).
// P^T -> PV B-frag fully in-register: 8 cvt_pk + 4 permlane32_swap per tile.
// Register double-buffered K/V prefetch (unroll-2). No LDS, no barriers.
// Scores pre-scaled by scale*log2e (folded into Wq) -> exp2 softmax.
// ---------------------------------------------------------------------------
#if __has_builtin(__builtin_amdgcn_permlane32_swap)
typedef unsigned int u32x2v __attribute__((ext_vector_type(2)));
#define PSWAP(a_, b_) do { u32x2v r_ = __builtin_amdgcn_permlane32_swap((a_), (b_), false, false); (a_) = r_[0]; (b_) = r_[1]; } while(0)
#else
#define PSWAP(a_, b_) asm("s_nop 1\n\tv_permlane32_swap_b32 %0, %1" : "+v"(a_), "+v"(b_))
#endif

#define LOADKV(K0_,K1_,V0_,V1_, kvb_) do { \
  const short* kp_ = Kb + (size_t)((kvb_) + l31)*DH + hi8; \
  K0_ = *(const bf16x8*)kp_; K1_ = *(const bf16x8*)(kp_ + 16); \
  const short* vp_ = Vb + (size_t)l31*SEQ + (kvb_) + hi8; \
  V0_ = *(const bf16x8*)vp_; V1_ = *(const bf16x8*)(vp_ + 16); \
} while(0)

#define ATTN_TILE(K0_, K1_, V0_, V1_) do { \
  f32x16 S_ = __builtin_amdgcn_mfma_f32_32x32x16_bf16(K0_, Q0, zf16, 0,0,0); \
  S_ = __builtin_amdgcn_mfma_f32_32x32x16_bf16(K1_, Q1, S_, 0,0,0); \
  float gm_ = S_[0]; \
  _Pragma("unroll") for (int r_=1;r_<16;r_++) gm_ = fmaxf(gm_, S_[r_]); \
  gm_ = fmaxf(gm_, __shfl_xor(gm_, 32)); \
  if (!__all(gm_ - mrun <= 8.f)) { \
    float mnew_ = fmaxf(mrun, gm_); \
    float corr_ = __builtin_amdgcn_exp2f(mrun - mnew_); \
    mrun = mnew_; lrun *= corr_; \
    _Pragma("unroll") for (int r_=0;r_<16;r_++) O[r_] *= corr_; \
  } \
  float p_[16]; float rs_ = 0.f; \
  _Pragma("unroll") for (int r_=0;r_<16;r_++){ p_[r_] = __builtin_amdgcn_exp2f(S_[r_]-mrun); rs_ += p_[r_]; } \
  rs_ += __shfl_xor(rs_, 32); lrun += rs_; \
  uint32_t pa_, pb_, pc_, pd_; \
  asm("v_cvt_pk_bf16_f32 %0, %1, %2" : "=v"(pa_) : "v"(p_[0]), "v"(p_[1])); \
  asm("v_cvt_pk_bf16_f32 %0, %1, %2" : "=v"(pb_) : "v"(p_[2]), "v"(p_[3])); \
  asm("v_cvt_pk_bf16_f32 %0, %1, %2" : "=v"(pc_) : "v"(p_[4]), "v"(p_[5])); \
  asm("v_cvt_pk_bf16_f32 %0, %1, %2" : "=v"(pd_) : "v"(p_[6]), "v"(p_[7])); \
  PSWAP(pa_, pc_); PSWAP(pb_, pd_); \
  { u32x4 w_ = {pa_, pb_, pc_, pd_}; \
    O = __builtin_amdgcn_mfma_f32_32x32x16_bf16(V0_, __builtin_bit_cast(bf16x8, w_), O, 0,0,0); } \
  asm("v_cvt_pk_bf16_f32 %0, %1, %2" : "=v"(pa_) : "v"(p_[8]),  "v"(p_[9])); \
  asm("v_cvt_pk_bf16_f32 %0, %1, %2" : "=v"(pb_) : "v"(p_[10]), "v"(p_[11])); \
  asm("v_cvt_pk_bf16_f32 %0, %1, %2" : "=v"(pc_) : "v"(p_[12]), "v"(p_[13])); \
  asm("v_cvt_pk_bf16_f32 %0, %1, %2" : "=v"(pd_) : "v"(p_[14]), "v"(p_[15])); \
  PSWAP(pa_, pc_); PSWAP(pb_, pd_); \
  { u32x4 w_ = {pa_, pb_, pc_, pd_}; \
    O = __builtin_amdgcn_mfma_f32_32x32x16_bf16(V1_, __builtin_bit_cast(bf16x8, w_), O, 0,0,0); } \
} while(0)

__global__ __launch_bounds__(256) void attn(
    const short* __restrict__ Qh, const short* __restrict__ Kh,
    const short* __restrict__ Vt, short* __restrict__ ctx)
{
  const int wid = threadIdx.x >> 6, lane = threadIdx.x & 63;
  const int l31 = lane & 31, hi8 = (lane >> 5)*8;
  const int bh = blockIdx.y;
  const int q0 = blockIdx.x*128 + wid*32;

  const short* Kb = Kh + (size_t)bh*SEQ*DH;
  const short* Vb = Vt + (size_t)bh*DH*SEQ;

  // Q B-frags over the two d-chunks: (q = q0+l31, k = d = c*16 + hi*8 + j)
  const short* qp = Qh + ((size_t)bh*SEQ + q0 + l31)*DH + hi8;
  const bf16x8 Q0 = *(const bf16x8*)(qp);
  const bf16x8 Q1 = *(const bf16x8*)(qp + 16);

  f32x16 O = {};
  float mrun = -1e30f, lrun = 0.f;
  const f32x16 zf16 = {};

  bf16x8 Ka0,Ka1,Va0,Va1, Kc0,Kc1,Vc0,Vc1;
  LOADKV(Ka0,Ka1,Va0,Va1, 0);

  for (int t = 0; t < SEQ/32; t += 2) {
    LOADKV(Kc0,Kc1,Vc0,Vc1, (t+1)*32);
    ATTN_TILE(Ka0,Ka1,Va0,Va1);
    LOADKV(Ka0,Ka1,Va0,Va1, ((t+2)&(SEQ/32-1))*32);
    ATTN_TILE(Kc0,Kc1,Vc0,Vc1);
  }

  // O^T lane layout: q = l31, d = (reg&3) + 8*(reg>>2) + (hi8>>1)
  const int bb = bh >> 3, hh = bh & 7;
  const float inv = 1.0f / lrun;
  short* cp = ctx + ((size_t)(bb*SEQ) + q0 + l31)*DM + hh*DH + (hi8 >> 1);
  #pragma unroll
  for (int rg=0; rg<4; ++rg) {
    s16x4 o;
    #pragma unroll
    for (int r=0;r<4;r++) o[r] = f2bf(O[rg*4+r]*inv);
    *(s16x4*)(cp + rg*8) = o;
  }
}

// ---------------------------------------------------------------------------
// out = ctx @ Wo^T + bo; x = out + query; LayerNorm(x). 1 wave/block,
// 512 blocks so all CUs are busy. Wo pre-converted bf16.
// ---------------------------------------------------------------------------
__global__ __launch_bounds__(64) void out_ln(
    const short* __restrict__ ctx, const short* __restrict__ Wob,
    const float* __restrict__ bo, const float* __restrict__ resid,
    const float* __restrict__ ln_g, const float* __restrict__ ln_b,
    float* __restrict__ out)
{
  const int lane = threadIdx.x;
  const int lr = lane & 15, lg = lane >> 4;
  const int m0 = blockIdx.x*16;

  f32x4 acc[16] = {};
  #pragma unroll
  for (int kc=0; kc<8; ++kc) {
    const int k0 = kc*32 + lg*8;
    bf16x8 a = *(const bf16x8*)(ctx + (size_t)(m0 + lr)*DM + k0);
    #pragma unroll
    for (int nf=0; nf<16; ++nf) {
      bf16x8 b = *(const bf16x8*)(Wob + (size_t)(nf*16 + lr)*DM + k0);
      acc[nf] = __builtin_amdgcn_mfma_f32_16x16x32_bf16(a, b, acc[nf], 0,0,0);
    }
  }

  #pragma unroll
  for (int r=0;r<4;r++) {
    const int m = m0 + lg*4 + r;
    float xv[16]; float s = 0.f, s2 = 0.f;
    #pragma unroll
    for (int nf=0; nf<16; ++nf) {
      const int col = nf*16 + lr;
      float v = acc[nf][r] + bo[col] + resid[(size_t)m*DM + col];
      xv[nf] = v; s += v; s2 += v*v;
    }
    #pragma unroll
    for (int off=1; off<16; off<<=1) { s += __shfl_xor(s, off); s2 += __shfl_xor(s2, off); }
    const float mean = s * (1.0f/DM);
    const float var  = s2 * (1.0f/DM) - mean*mean;
    const float rstd = rsqrtf(var + 1e-5f);
    #pragma unroll
    for (int nf=0; nf<16; ++nf) {
      const int col = nf*16 + lr;
      out[(size_t)m*DM + col] = (xv[nf] - mean)*rstd*ln_g[col] + ln_b[col];
    }
  }
}

extern "C" void kernel_launch(void* const* d_in, const int* in_sizes, int n_in,
                              void* d_out, int out_size, void* d_ws, size_t ws_size,
                              hipStream_t stream) {
  const float* query = (const float*)d_in[0];
  const float* key   = (const float*)d_in[1];
  const float* value = (const float*)d_in[2];
  const float* Wq    = (const float*)d_in[3];
  const float* bq    = (const float*)d_in[4];
  const float* Wk    = (const float*)d_in[5];
  const float* bk    = (const float*)d_in[6];
  const float* Wv    = (const float*)d_in[7];
  const float* bv    = (const float*)d_in[8];
  const float* Wo    = (const float*)d_in[9];
  const float* bo    = (const float*)d_in[10];
  const float* ln_g  = (const float*)d_in[11];
  const float* ln_b  = (const float*)d_in[12];
  float* out = (float*)d_out;

  const size_t HSZ = (size_t)NB*NHEADS*SEQ*DH;   // 2,097,152
  short* Qh  = (short*)d_ws;
  short* Kh  = Qh + HSZ;
  short* Vt  = Kh + HSZ;
  short* ctx = Vt + HSZ;
  short* Wqb = ctx + (size_t)MTOT*DM;
  short* Wkb = Wqb + DM*DM;
  short* Wvb = Wkb + DM*DM;
  short* Wob = Wvb + DM*DM;   // total ws: ~17 MB

  prep<<<dim3(128), 256, 0, stream>>>(Wq, Wk, Wv, Wo, Wqb, Wkb, Wvb, Wob);
  qkv_proj<<<dim3(MTOT/64, 4, 3), 256, 0, stream>>>(
      query, key, value, Wqb, Wkb, Wvb, bq, bk, bv, Qh, Kh, Vt);
  attn<<<dim3(SEQ/128, NB*NHEADS), 256, 0, stream>>>(Qh, Kh, Vt, ctx);
  out_ln<<<dim3(MTOT/16), 64, 0, stream>>>(ctx, Wob, bo, query, ln_g, ln_b, out);
}